// Round 1
// baseline (1145.429 us; speedup 1.0000x reference)
//
#include <hip/hip_runtime.h>
#include <math.h>

#define T_STEPS 512
#define NF 4
#define HID 32
#define GROUPS 8          // batch rows per 256-thread block (32 lanes each)
#define BN_EPS 1e-5f

__device__ __forceinline__ float fsigmoid(float x) {
  // 1/(1+exp(-x)) via v_exp_f32 + v_rcp_f32 (~1e-6 rel err, fine vs 1e-2 threshold)
  return __builtin_amdgcn_rcpf(1.0f + __expf(-x));
}
__device__ __forceinline__ float ftanh(float x) {
  // tanh(x) = 2*sigmoid(2x) - 1; saturates correctly via exp->inf -> rcp->0
  return fmaf(__builtin_amdgcn_rcpf(1.0f + __expf(-2.0f * x)), 2.0f, -1.0f);
}

__global__ __launch_bounds__(256) void hedge_kernel(
    const float* __restrict__ x,
    const float* __restrict__ bn_g, const float* __restrict__ bn_b,
    const float* __restrict__ bn_m, const float* __restrict__ bn_v,
    const float* __restrict__ W_ih, const float* __restrict__ b_ih,
    const float* __restrict__ W_hh, const float* __restrict__ b_hh,
    const float* __restrict__ W1,   const float* __restrict__ b1,
    const float* __restrict__ W2,   const float* __restrict__ b2,
    float* __restrict__ out)
{
  // W_hh repacked gate-major: sWp[k*128 + j*4 + gate]; one b128 per (k, lane)
  __shared__ __align__(16) float sWp[HID * 4 * HID];   // 4096 floats = 16 KB
  __shared__ __align__(16) float sh[GROUPS * HID];     // per-group hidden state

  const int tid = threadIdx.x;
  const int j   = tid & 31;          // hidden unit handled by this lane
  const int grp = tid >> 5;          // batch group within block
  const int b   = blockIdx.x * GROUPS + grp;

  // ---- stage W_hh -> LDS, repacked [k][j][gate] (coalesced global reads)
  for (int i = tid * 4; i < 4096; i += 1024) {
    float4 v = *(const float4*)&W_hh[i];     // row r = i>>5, cols k..k+3 (k = i&31)
    int r = i >> 5, k = i & 31;
    int g = r >> 5, jj = r & 31;
    sWp[(k + 0) * 128 + jj * 4 + g] = v.x;
    sWp[(k + 1) * 128 + jj * 4 + g] = v.y;
    sWp[(k + 2) * 128 + jj * 4 + g] = v.z;
    sWp[(k + 3) * 128 + jj * 4 + g] = v.w;
  }
  sh[tid] = 0.0f;   // h0 = 0 (256 entries, 256 threads)

  // ---- fold BatchNorm into W_ih and bias (per-lane registers)
  float scale[5], shift[5];
  #pragma unroll
  for (int f = 0; f < 5; ++f) {
    float s = bn_g[f] * rsqrtf(bn_v[f] + BN_EPS);
    scale[f] = s;
    shift[f] = fmaf(-bn_m[f], s, bn_b[f]);
  }
  float4 wip[5];     // wip[f] = (i,f,g,o) gate weights for input feature f
  float4 bias;
  {
    float bb[4];
    #pragma unroll
    for (int g = 0; g < 4; ++g) {
      const int r = g * HID + j;
      float acc = b_ih[r] + b_hh[r];
      #pragma unroll
      for (int f = 0; f < 5; ++f) {
        float w = W_ih[r * 5 + f];
        (&wip[f].x)[g] = w * scale[f];
        acc = fmaf(w, shift[f], acc);
      }
      bb[g] = acc;
    }
    bias = make_float4(bb[0], bb[1], bb[2], bb[3]);
  }
  // decision-MLP row for this lane
  float w1r[HID];
  #pragma unroll
  for (int k0 = 0; k0 < 8; ++k0)
    *(float4*)&w1r[k0 * 4] = *(const float4*)&W1[j * HID + k0 * 4];
  const float b1j = b1[j];
  const float w2j = W2[j];
  const float b2s = b2[0];

  __syncthreads();

  const float* xb = x + (size_t)b * (T_STEPS * NF);
  float*       ob = out + (size_t)b * T_STEPS;
  const float4* wp4 = (const float4*)sWp;            // wp4[k*32 + j]
  const float4* sh4 = (const float4*)(sh + grp * HID);

  float h = 0.0f, c = 0.0f, d = 0.0f;
  float4 xt = *(const float4*)xb;                    // prefetched x_t

  #pragma unroll 1
  for (int t = 0; t < T_STEPS; ++t) {
    const int tn = (t + 1 < T_STEPS) ? t + 1 : t;
    const float4 xnext = *(const float4*)(xb + tn * NF);   // prefetch t+1

    // ---- gates = W_hh·h + W_ih'·[x,d] + bias'
    float gi = bias.x, gf = bias.y, gg = bias.z, go = bias.w;
    #pragma unroll
    for (int k0 = 0; k0 < 8; ++k0) {
      const float4 h4 = sh4[k0];                     // broadcast read
      #pragma unroll
      for (int kk = 0; kk < 4; ++kk) {
        const float hk = (&h4.x)[kk];
        const float4 w = wp4[(k0 * 4 + kk) * 32 + j];
        gi = fmaf(w.x, hk, gi);
        gf = fmaf(w.y, hk, gf);
        gg = fmaf(w.z, hk, gg);
        go = fmaf(w.w, hk, go);
      }
    }
    gi = fmaf(wip[0].x, xt.x, gi); gf = fmaf(wip[0].y, xt.x, gf);
    gg = fmaf(wip[0].z, xt.x, gg); go = fmaf(wip[0].w, xt.x, go);
    gi = fmaf(wip[1].x, xt.y, gi); gf = fmaf(wip[1].y, xt.y, gf);
    gg = fmaf(wip[1].z, xt.y, gg); go = fmaf(wip[1].w, xt.y, go);
    gi = fmaf(wip[2].x, xt.z, gi); gf = fmaf(wip[2].y, xt.z, gf);
    gg = fmaf(wip[2].z, xt.z, gg); go = fmaf(wip[2].w, xt.z, go);
    gi = fmaf(wip[3].x, xt.w, gi); gf = fmaf(wip[3].y, xt.w, gf);
    gg = fmaf(wip[3].z, xt.w, gg); go = fmaf(wip[3].w, xt.w, go);
    gi = fmaf(wip[4].x, d,    gi); gf = fmaf(wip[4].y, d,    gf);
    gg = fmaf(wip[4].z, d,    gg); go = fmaf(wip[4].w, d,    go);

    const float I = fsigmoid(gi);
    const float F = fsigmoid(gf);
    const float G = ftanh(gg);
    const float O = fsigmoid(go);
    c = fmaf(F, c, I * G);
    h = O * ftanh(c);

    __syncthreads();                 // all reads of old h done
    sh[grp * HID + j] = h;
    __syncthreads();                 // new h visible

    // ---- decision MLP: d = sigmoid(relu(h@W1.T + b1) @ W2.T + b2)
    float m = b1j;
    #pragma unroll
    for (int k0 = 0; k0 < 8; ++k0) {
      const float4 h4 = sh4[k0];     // broadcast read of new h
      m = fmaf(w1r[k0 * 4 + 0], h4.x, m);
      m = fmaf(w1r[k0 * 4 + 1], h4.y, m);
      m = fmaf(w1r[k0 * 4 + 2], h4.z, m);
      m = fmaf(w1r[k0 * 4 + 3], h4.w, m);
    }
    m = fmaxf(m, 0.0f) * w2j;
    #pragma unroll
    for (int off = 16; off > 0; off >>= 1)
      m += __shfl_xor(m, off, 32);   // 32-lane group reduction (all lanes get sum)
    d = fsigmoid(m + b2s);

    if (j == 0) ob[t] = d;
    xt = xnext;
  }
}

extern "C" void kernel_launch(void* const* d_in, const int* in_sizes, int n_in,
                              void* d_out, int out_size, void* d_ws, size_t ws_size,
                              hipStream_t stream) {
  const float* x    = (const float*)d_in[0];
  const float* bn_g = (const float*)d_in[1];
  const float* bn_b = (const float*)d_in[2];
  const float* bn_m = (const float*)d_in[3];
  const float* bn_v = (const float*)d_in[4];
  const float* W_ih = (const float*)d_in[5];
  const float* b_ih = (const float*)d_in[6];
  const float* W_hh = (const float*)d_in[7];
  const float* b_hh = (const float*)d_in[8];
  const float* W1   = (const float*)d_in[9];
  const float* b1   = (const float*)d_in[10];
  const float* W2   = (const float*)d_in[11];
  const float* b2   = (const float*)d_in[12];
  float* out = (float*)d_out;

  const int B = in_sizes[0] / (T_STEPS * NF);   // 8192
  const int grid = B / GROUPS;                  // 1024 blocks x 256 threads

  hipLaunchKernelGGL(hedge_kernel, dim3(grid), dim3(256), 0, stream,
                     x, bn_g, bn_b, bn_m, bn_v, W_ih, b_ih, W_hh, b_hh,
                     W1, b1, W2, b2, out);
}

// Round 3
// 915.209 us; speedup vs baseline: 1.2515x; 1.2515x over previous
//
#include <hip/hip_runtime.h>
#include <math.h>

#define T_STEPS 512
#define NF 4
#define HID 32
#define GROUPS 8          // batch rows per 256-thread block (one row per 32-lane group)
#define BN_EPS 1e-5f

typedef float f32x2 __attribute__((ext_vector_type(2)));
typedef float f32x4 __attribute__((ext_vector_type(4)));

// packed fp32 FMA: lowers to v_pk_fma_f32 on gfx90a+ (2x fp32 rate)
__device__ __forceinline__ f32x2 fma2(f32x2 a, f32x2 b, f32x2 c) {
  return __builtin_elementwise_fma(a, b, c);
}
__device__ __forceinline__ float fsigmoid(float x) {
  // 1/(1+exp(-x)); ~1e-6 rel err, validated round 1 (absmax 2e-3 vs 9.8e-3 thr)
  return __builtin_amdgcn_rcpf(1.0f + __expf(-x));
}
__device__ __forceinline__ float ftanh(float x) {
  return fmaf(__builtin_amdgcn_rcpf(1.0f + __expf(-2.0f * x)), 2.0f, -1.0f);
}
template <int CTRL>
__device__ __forceinline__ float dpp_add(float v) {
  int s = __builtin_amdgcn_update_dpp(0, __builtin_bit_cast(int, v), CTRL, 0xf, 0xf, true);
  return v + __builtin_bit_cast(float, s);
}
// sum over each 32-lane half of the wave; result broadcast to all lanes of the half.
// Pure VALU (DPP) — no LDS pipe, unlike __shfl_xor (ds_bpermute).
__device__ __forceinline__ float group_reduce32(float v, bool upper_half) {
  v = dpp_add<0x111>(v);   // row_shr:1  (within 16-lane rows, 0-fill)
  v = dpp_add<0x112>(v);   // row_shr:2
  v = dpp_add<0x114>(v);   // row_shr:4
  v = dpp_add<0x118>(v);   // row_shr:8  -> lane15/31/47/63 hold row sums
  v = dpp_add<0x142>(v);   // row_bcast:15 -> lane31 = sum(0..31), lane63 = sum(32..63)
  float lo = __builtin_bit_cast(float, __builtin_amdgcn_readlane(__builtin_bit_cast(int, v), 31));
  float hi = __builtin_bit_cast(float, __builtin_amdgcn_readlane(__builtin_bit_cast(int, v), 63));
  return upper_half ? hi : lo;
}

__global__ __launch_bounds__(256, 2) void hedge_kernel(
    const float* __restrict__ x,
    const float* __restrict__ bn_g, const float* __restrict__ bn_b,
    const float* __restrict__ bn_m, const float* __restrict__ bn_v,
    const float* __restrict__ W_ih, const float* __restrict__ b_ih,
    const float* __restrict__ W_hh, const float* __restrict__ b_hh,
    const float* __restrict__ W1,   const float* __restrict__ b1,
    const float* __restrict__ W2,   const float* __restrict__ b2,
    float* __restrict__ out)
{
  __shared__ float sh[GROUPS * HID];   // 1 KB: h broadcast only (wave-local, no barriers)

  const int tid = threadIdx.x;
  const int j   = tid & 31;            // hidden unit owned by this lane
  const int grp = tid >> 5;            // batch row within block
  const bool upper = (tid & 32) != 0;  // which 32-half of the wave
  const int b   = blockIdx.x * GROUPS + grp;

  // ---- fold BatchNorm (z*scale + shift) into W_ih' and bias
  float scale[5], shift[5];
  #pragma unroll
  for (int f = 0; f < 5; ++f) {
    float s = bn_g[f] * rsqrtf(bn_v[f] + BN_EPS);
    scale[f] = s;
    shift[f] = fmaf(-bn_m[f], s, bn_b[f]);
  }

  // ---- ALL weights in registers (this was the round-1 LDS-pipe bottleneck)
  f32x2 wh[4][16];   // W_hh col j, gate-major, k-pairs   (128 VGPRs)
  f32x2 wx[4][2];    // BN-scaled W_ih features 0..3      (16 VGPRs)
  float wd[4];       // BN-scaled W_ih feature 4 (prev d) (4 VGPRs)
  float bias[4];     // b_ih + b_hh + BN shift fold       (4 VGPRs)
  #pragma unroll
  for (int g = 0; g < 4; ++g) {
    const int r = g * HID + j;
    const float* Wr = &W_ih[r * 5];
    float acc = b_ih[r] + b_hh[r];
    float ws[5];
    #pragma unroll
    for (int f = 0; f < 5; ++f) {
      float w = Wr[f];
      ws[f] = w * scale[f];
      acc = fmaf(w, shift[f], acc);
    }
    wx[g][0] = (f32x2){ws[0], ws[1]};
    wx[g][1] = (f32x2){ws[2], ws[3]};
    wd[g] = ws[4];
    bias[g] = acc;
    #pragma unroll
    for (int p = 0; p < 16; ++p)
      wh[g][p] = *(const f32x2*)&W_hh[r * HID + 2 * p];
  }
  f32x2 w1p[16];     // decision-MLP row j as k-pairs (32 VGPRs)
  #pragma unroll
  for (int p = 0; p < 16; ++p)
    w1p[p] = *(const f32x2*)&W1[j * HID + 2 * p];
  const float b1j = b1[j];
  const float w2j = W2[j];
  const float b2s = b2[0];

  const float* xb = x + (size_t)b * (T_STEPS * NF);
  float*       ob = out + (size_t)b * T_STEPS;
  const f32x4* sh4 = (const f32x4*)(sh + grp * HID);

  float c = 0.0f, h = 0.0f, d = 0.0f;

  // gate pre-accumulators for step t: bias + x_t (h_{-1}=0, d_{-1}=0 contribute 0)
  f32x2 acc[4];
  {
    f32x4 x0 = *(const f32x4*)xb;
    f32x2 p0 = (f32x2){x0.x, x0.y}, p1 = (f32x2){x0.z, x0.w};
    #pragma unroll
    for (int g = 0; g < 4; ++g) {
      acc[g] = (f32x2){bias[g], 0.0f};
      acc[g] = fma2(wx[g][0], p0, acc[g]);
      acc[g] = fma2(wx[g][1], p1, acc[g]);
    }
  }

  #pragma unroll 1
  for (int t = 0; t < T_STEPS; ++t) {
    const int tn = (t + 1 < T_STEPS) ? t + 1 : t;
    const f32x4 xn = *(const f32x4*)(xb + tn * NF);   // prefetch x_{t+1}

    // ---- LSTM cell for step t (acc already holds bias + x_t + h_{t-1} + d_{t-1} terms)
    const float gi = acc[0].x + acc[0].y;
    const float gf = acc[1].x + acc[1].y;
    const float gg = acc[2].x + acc[2].y;
    const float go = acc[3].x + acc[3].y;
    const float I = fsigmoid(gi);
    const float F = fsigmoid(gf);
    const float G = ftanh(gg);
    const float O = fsigmoid(go);
    c = fmaf(F, c, I * G);
    h = O * ftanh(c);

    sh[grp * HID + j] = h;   // same-wave producer/consumer: lgkmcnt orders it, no barrier

    // ---- re-init gate accumulators for t+1: bias + x_{t+1}
    {
      f32x2 p0 = (f32x2){xn.x, xn.y}, p1 = (f32x2){xn.z, xn.w};
      #pragma unroll
      for (int g = 0; g < 4; ++g) {
        acc[g] = (f32x2){bias[g], 0.0f};
        acc[g] = fma2(wx[g][0], p0, acc[g]);
        acc[g] = fma2(wx[g][1], p1, acc[g]);
      }
    }

    // ---- single pass over h_t: feeds MLP(t) AND gate h-term(t+1)
    f32x2 macc = (f32x2){b1j, 0.0f};
    #pragma unroll
    for (int i = 0; i < 8; ++i) {
      const f32x4 hv = sh4[i];                        // broadcast ds_read_b128
      const f32x2 p0 = (f32x2){hv.x, hv.y};
      const f32x2 p1 = (f32x2){hv.z, hv.w};
      acc[0] = fma2(wh[0][2*i], p0, acc[0]); acc[0] = fma2(wh[0][2*i+1], p1, acc[0]);
      acc[1] = fma2(wh[1][2*i], p0, acc[1]); acc[1] = fma2(wh[1][2*i+1], p1, acc[1]);
      acc[2] = fma2(wh[2][2*i], p0, acc[2]); acc[2] = fma2(wh[2][2*i+1], p1, acc[2]);
      acc[3] = fma2(wh[3][2*i], p0, acc[3]); acc[3] = fma2(wh[3][2*i+1], p1, acc[3]);
      macc   = fma2(w1p[2*i],   p0, macc);   macc   = fma2(w1p[2*i+1],  p1, macc);
    }

    // ---- decision MLP tail: relu, W2 dot (cross-lane), sigmoid
    const float m = macc.x + macc.y;
    const float r = fmaxf(m, 0.0f) * w2j;
    const float s = group_reduce32(r, upper);
    d = fsigmoid(s + b2s);

    // d_t term of gates(t+1)
    #pragma unroll
    for (int g = 0; g < 4; ++g)
      acc[g].x = fmaf(wd[g], d, acc[g].x);

    if (j == 0) ob[t] = d;
  }
}

extern "C" void kernel_launch(void* const* d_in, const int* in_sizes, int n_in,
                              void* d_out, int out_size, void* d_ws, size_t ws_size,
                              hipStream_t stream) {
  const float* x    = (const float*)d_in[0];
  const float* bn_g = (const float*)d_in[1];
  const float* bn_b = (const float*)d_in[2];
  const float* bn_m = (const float*)d_in[3];
  const float* bn_v = (const float*)d_in[4];
  const float* W_ih = (const float*)d_in[5];
  const float* b_ih = (const float*)d_in[6];
  const float* W_hh = (const float*)d_in[7];
  const float* b_hh = (const float*)d_in[8];
  const float* W1   = (const float*)d_in[9];
  const float* b1   = (const float*)d_in[10];
  const float* W2   = (const float*)d_in[11];
  const float* b2   = (const float*)d_in[12];
  float* out = (float*)d_out;

  const int B = in_sizes[0] / (T_STEPS * NF);   // 8192
  const int grid = B / GROUPS;                  // 1024 blocks x 256 threads

  hipLaunchKernelGGL(hedge_kernel, dim3(grid), dim3(256), 0, stream,
                     x, bn_g, bn_b, bn_m, bn_v, W_ih, b_ih, W_hh, b_hh,
                     W1, b1, W2, b2, out);
}